// Round 2
// baseline (1460.524 us; speedup 1.0000x reference)
//
#include <hip/hip_runtime.h>

typedef _Float16 f16;
typedef f16 f16x8 __attribute__((ext_vector_type(8)));
typedef float f32x4 __attribute__((ext_vector_type(4)));

#define BD 2048
#define SD 32
#define DD 1024
#define HD 1024
#define MD 4096
#define KD 32
#define PADK 40  // 32 k-halfs + 8 pad: 80B row stride, breaks LDS bank cycling

// ---------------- transpose f32 [R,C] -> f16 [C,R] ----------------
__global__ void k_transpose_f16(const float* __restrict__ in, f16* __restrict__ out,
                                int R, int C) {
  __shared__ float tile[32][33];
  int c0 = blockIdx.x * 32, r0 = blockIdx.y * 32;
  int tx = threadIdx.x & 31, ty = threadIdx.x >> 5;  // ty in 0..7
#pragma unroll
  for (int i = 0; i < 4; ++i) {
    int r = ty + i * 8;
    tile[r][tx] = in[(size_t)(r0 + r) * C + c0 + tx];
  }
  __syncthreads();
#pragma unroll
  for (int i = 0; i < 4; ++i) {
    int r = ty + i * 8;
    out[(size_t)(c0 + r) * R + r0 + tx] = (f16)tile[tx][r];
  }
}

// ---------------- transpose f32 [R,C] -> split f16 hi/lo [C,R] ----------------
__global__ void k_transpose_split(const float* __restrict__ in, f16* __restrict__ outHi,
                                  f16* __restrict__ outLo, int R, int C) {
  __shared__ float tile[32][33];
  int c0 = blockIdx.x * 32, r0 = blockIdx.y * 32;
  int tx = threadIdx.x & 31, ty = threadIdx.x >> 5;
#pragma unroll
  for (int i = 0; i < 4; ++i) {
    int r = ty + i * 8;
    tile[r][tx] = in[(size_t)(r0 + r) * C + c0 + tx];
  }
  __syncthreads();
#pragma unroll
  for (int i = 0; i < 4; ++i) {
    int r = ty + i * 8;
    float v = tile[tx][r];
    f16 h = (f16)v;
    size_t o = (size_t)(c0 + r) * R + r0 + tx;
    outHi[o] = h;
    outLo[o] = (f16)(v - (float)h);
  }
}

// ---------------- split f32 -> f16 hi/lo flat (n8 = count/8) ----------------
__global__ void k_split(const float* __restrict__ in, f16* __restrict__ hi,
                        f16* __restrict__ lo, int n8) {
  int i = blockIdx.x * 256 + threadIdx.x;
  if (i >= n8) return;
  const float4* p = (const float4*)in + (size_t)i * 2;
  float4 a = p[0], b = p[1];
  float v[8] = {a.x, a.y, a.z, a.w, b.x, b.y, b.z, b.w};
  f16x8 h, l;
#pragma unroll
  for (int e = 0; e < 8; ++e) {
    h[e] = (f16)v[e];
    l[e] = (f16)(v[e] - (float)h[e]);
  }
  *((f16x8*)hi + i) = h;
  *((f16x8*)lo + i) = l;
}

// ---------------- NT GEMM: C[M,N] = A[M,K] * B[N,K]^T ----------------
// 256 thr = 4 waves; block tile 128x128; K-chunk 32; wave tile 64x64 (4x4 MFMA tiles).
// SPLIT=1: A fp32 split hi/lo in staging, B pre-split (Bhi,Blo); 3-pass MFMA
//          (hi*hi + hi*lo + lo*hi) -> fp32-equivalent precision.
// SPLIT=0: A fp16, B=Bhi fp16, 1-pass.
// EPI 0: C[row,col] = v
// EPI 1: v' = tanh(v + bias[col]); mean over 32-row groups -> C[(row/32), col]
// EPI 2: C[row,col] = tanh(v + bias[col])
template <int SPLIT, int EPI>
__global__ __launch_bounds__(256) void k_gemm_nt(const void* __restrict__ Ap,
                                                 const f16* __restrict__ Bhi,
                                                 const f16* __restrict__ Blo,
                                                 float* __restrict__ C,
                                                 const float* __restrict__ bias,
                                                 int M, int N, int K) {
  __shared__ f16 As[128 * PADK];
  __shared__ f16 Bs[128 * PADK];
  __shared__ f16 Asl[SPLIT ? 128 * PADK : 8];
  __shared__ f16 Bsl[SPLIT ? 128 * PADK : 8];
  const int n0 = blockIdx.x * 128, m0 = blockIdx.y * 128;
  const int t = threadIdx.x;
  const int lane = t & 63, w = t >> 6;
  const int wm = w >> 1, wn = w & 1;
  const int quad = lane >> 4, l16 = lane & 15;
  const int srow = t >> 2, sseg = t & 3;  // staging: row srow(+64), 8-half segment sseg

  f32x4 acc[4][4] = {};

  for (int kc = 0; kc < K; kc += 32) {
#pragma unroll
    for (int rep = 0; rep < 2; ++rep) {
      int row = srow + rep * 64;
      if (SPLIT) {
        const float* g = (const float*)Ap + (size_t)(m0 + row) * K + kc + sseg * 8;
        float4 u0 = *(const float4*)g;
        float4 u1 = *(const float4*)(g + 4);
        float v[8] = {u0.x, u0.y, u0.z, u0.w, u1.x, u1.y, u1.z, u1.w};
        f16x8 h, l;
#pragma unroll
        for (int e = 0; e < 8; ++e) {
          h[e] = (f16)v[e];
          l[e] = (f16)(v[e] - (float)h[e]);
        }
        *(f16x8*)(As + row * PADK + sseg * 8) = h;
        *(f16x8*)(Asl + row * PADK + sseg * 8) = l;
        size_t bo = (size_t)(n0 + row) * K + kc + sseg * 8;
        *(f16x8*)(Bs + row * PADK + sseg * 8) = *(const f16x8*)(Bhi + bo);
        *(f16x8*)(Bsl + row * PADK + sseg * 8) = *(const f16x8*)(Blo + bo);
      } else {
        const f16* g = (const f16*)Ap + (size_t)(m0 + row) * K + kc + sseg * 8;
        *(f16x8*)(As + row * PADK + sseg * 8) = *(const f16x8*)g;
        const f16* gb = Bhi + (size_t)(n0 + row) * K + kc + sseg * 8;
        *(f16x8*)(Bs + row * PADK + sseg * 8) = *(const f16x8*)gb;
      }
    }
    __syncthreads();
    f16x8 ah[4], bh[4];
#pragma unroll
    for (int i = 0; i < 4; ++i) {
      ah[i] = *(const f16x8*)(As + (wm * 64 + i * 16 + l16) * PADK + quad * 8);
      bh[i] = *(const f16x8*)(Bs + (wn * 64 + i * 16 + l16) * PADK + quad * 8);
    }
    if (SPLIT) {
      f16x8 al[4], bl[4];
#pragma unroll
      for (int i = 0; i < 4; ++i) {
        al[i] = *(const f16x8*)(Asl + (wm * 64 + i * 16 + l16) * PADK + quad * 8);
        bl[i] = *(const f16x8*)(Bsl + (wn * 64 + i * 16 + l16) * PADK + quad * 8);
      }
#pragma unroll
      for (int i = 0; i < 4; ++i)
#pragma unroll
        for (int j = 0; j < 4; ++j) {
          acc[i][j] = __builtin_amdgcn_mfma_f32_16x16x32_f16(ah[i], bh[j], acc[i][j], 0, 0, 0);
          acc[i][j] = __builtin_amdgcn_mfma_f32_16x16x32_f16(ah[i], bl[j], acc[i][j], 0, 0, 0);
          acc[i][j] = __builtin_amdgcn_mfma_f32_16x16x32_f16(al[i], bh[j], acc[i][j], 0, 0, 0);
        }
    } else {
#pragma unroll
      for (int i = 0; i < 4; ++i)
#pragma unroll
        for (int j = 0; j < 4; ++j)
          acc[i][j] = __builtin_amdgcn_mfma_f32_16x16x32_f16(ah[i], bh[j], acc[i][j], 0, 0, 0);
    }
    __syncthreads();
  }

  if (EPI == 0) {
#pragma unroll
    for (int i = 0; i < 4; ++i) {
#pragma unroll
      for (int j = 0; j < 4; ++j) {
        int row = m0 + wm * 64 + i * 16 + quad * 4;
        int col = n0 + wn * 64 + j * 16 + l16;
        float* cp = C + (size_t)row * N + col;
#pragma unroll
        for (int r = 0; r < 4; ++r) cp[(size_t)r * N] = acc[i][j][r];
      }
    }
  } else if (EPI == 2) {
#pragma unroll
    for (int i = 0; i < 4; ++i) {
#pragma unroll
      for (int j = 0; j < 4; ++j) {
        int row = m0 + wm * 64 + i * 16 + quad * 4;
        int col = n0 + wn * 64 + j * 16 + l16;
        float bv = bias[col];
        float* cp = C + (size_t)row * N + col;
#pragma unroll
        for (int r = 0; r < 4; ++r) cp[(size_t)r * N] = tanhf(acc[i][j][r] + bv);
      }
    }
  } else {  // EPI == 1: tanh + mean over 32-row groups
#pragma unroll
    for (int j = 0; j < 4; ++j) {
      int col = n0 + wn * 64 + j * 16 + l16;
      float bv = bias[col];
      float g0 = 0.f, g1 = 0.f;
#pragma unroll
      for (int i = 0; i < 4; ++i) {
        float s = 0.f;
#pragma unroll
        for (int r = 0; r < 4; ++r) s += tanhf(acc[i][j][r] + bv);
        if (i < 2) g0 += s; else g1 += s;
      }
      g0 += __shfl_xor(g0, 16); g0 += __shfl_xor(g0, 32);
      g1 += __shfl_xor(g1, 16); g1 += __shfl_xor(g1, 32);
      if (quad == 0) {
        int grp = (m0 + wm * 64) >> 5;
        C[(size_t)grp * N + col] = g0 * (1.0f / 32.0f);
        C[(size_t)(grp + 1) * N + col] = g1 * (1.0f / 32.0f);
      }
    }
  }
}

// ---------------- gate: scale[b] = (0.5 + sigmoid(q.w_curv + b_curv)) / max(temp,1e-6) --------
__global__ void k_gate(const float* __restrict__ query, const float* __restrict__ w_curv,
                       const float* __restrict__ b_curv, const float* __restrict__ temp,
                       float* __restrict__ scale) {
  int b = blockIdx.x, t = threadIdx.x;
  float s = 0.f;
  for (int h = t; h < HD; h += 256) s += query[(size_t)b * HD + h] * w_curv[h];
#pragma unroll
  for (int off = 32; off; off >>= 1) s += __shfl_xor(s, off);
  __shared__ float red[4];
  if ((t & 63) == 0) red[t >> 6] = s;
  __syncthreads();
  if (t == 0) {
    float tot = red[0] + red[1] + red[2] + red[3] + b_curv[0];
    float g = 1.f / (1.f + expf(-tot));
    scale[b] = (0.5f + g) / fmaxf(temp[0], 1e-6f);
  }
}

// ---------------- top-32 per row (iterative argmax in LDS) ----------------
__global__ void k_topk(const float* __restrict__ sim, const float* __restrict__ scale,
                       int* __restrict__ idx, float* __restrict__ vals) {
  int b = blockIdx.x, t = threadIdx.x;
  __shared__ float sv[MD];
  __shared__ float rv[4];
  __shared__ int ri[4];
  for (int i = t; i < MD; i += 256) sv[i] = sim[(size_t)b * MD + i];
  __syncthreads();
  float sc = scale[b];
  for (int k = 0; k < KD; ++k) {
    float bv = -1e30f;
    int bi = 0x7fffffff;
    for (int i = t; i < MD; i += 256) {
      float v = sv[i];
      if (v > bv) { bv = v; bi = i; }
    }
#pragma unroll
    for (int off = 1; off < 64; off <<= 1) {
      float ov = __shfl_xor(bv, off);
      int oi = __shfl_xor(bi, off);
      if (ov > bv || (ov == bv && oi < bi)) { bv = ov; bi = oi; }
    }
    if ((t & 63) == 0) { rv[t >> 6] = bv; ri[t >> 6] = bi; }
    __syncthreads();
    if (t == 0) {
      float fv = rv[0];
      int fi = ri[0];
#pragma unroll
      for (int u = 1; u < 4; ++u)
        if (rv[u] > fv || (rv[u] == fv && ri[u] < fi)) { fv = rv[u]; fi = ri[u]; }
      idx[b * KD + k] = fi;
      vals[b * KD + k] = fv * sc;
      sv[fi] = -1e30f;
    }
    __syncthreads();
  }
}

// ---------------- row softmax f32 -> f16 ----------------
__global__ void k_softmax(const float* __restrict__ in, f16* __restrict__ out, int C) {
  int b = blockIdx.x, t = threadIdx.x;
  const float* row = in + (size_t)b * C;
  __shared__ float red[4];
  float m = -1e30f;
  for (int i = t; i < C; i += 256) m = fmaxf(m, row[i]);
#pragma unroll
  for (int off = 32; off; off >>= 1) m = fmaxf(m, __shfl_xor(m, off));
  if ((t & 63) == 0) red[t >> 6] = m;
  __syncthreads();
  m = fmaxf(fmaxf(red[0], red[1]), fmaxf(red[2], red[3]));
  __syncthreads();
  float s = 0.f;
  for (int i = t; i < C; i += 256) s += expf(row[i] - m);
#pragma unroll
  for (int off = 32; off; off >>= 1) s += __shfl_xor(s, off);
  if ((t & 63) == 0) red[t >> 6] = s;
  __syncthreads();
  s = red[0] + red[1] + red[2] + red[3];
  float inv = 1.f / s;
  for (int i = t; i < C; i += 256) out[(size_t)b * C + i] = (f16)(expf(row[i] - m) * inv);
}

// ---------------- combine: softmax(vals + act[idx]) weighted gather of memory_slots --------
__global__ void k_combine(const float* __restrict__ vals, const int* __restrict__ idx,
                          const float* __restrict__ act, const float* __restrict__ mem,
                          f16* __restrict__ read_h) {
  int b = blockIdx.x, t = threadIdx.x;
  __shared__ float comb[KD];
  __shared__ int sidx[KD];
  if (t < KD) {
    int id = idx[b * KD + t];
    sidx[t] = id;
    float e = vals[b * KD + t] + act[(size_t)b * MD + id];
    float m = e;
#pragma unroll
    for (int off = 16; off; off >>= 1) m = fmaxf(m, __shfl_xor(m, off));
    float p = expf(e - m);
    float s = p;
#pragma unroll
    for (int off = 16; off; off >>= 1) s += __shfl_xor(s, off);
    comb[t] = p / s;
  }
  __syncthreads();
  for (int h = t; h < HD; h += 256) {
    float a = 0.f;
#pragma unroll
    for (int k = 0; k < KD; ++k) a += comb[k] * mem[(size_t)sidx[k] * HD + h];
    read_h[(size_t)b * HD + h] = (f16)a;
  }
}

// ---------------- broadcast out_b[B,D] -> out[B,S,D] ----------------
__global__ void k_broadcast(const float4* __restrict__ src, float4* __restrict__ dst) {
  size_t v = (size_t)blockIdx.x * 256 + threadIdx.x;
  size_t d4 = v & 255;   // D/4 = 256 float4 per row
  size_t b = v >> 13;    // / (S * 256)
  dst[v] = src[b * 256 + d4];
}

extern "C" void kernel_launch(void* const* d_in, const int* in_sizes, int n_in,
                              void* d_out, int out_size, void* d_ws, size_t ws_size,
                              hipStream_t stream) {
  const float* x      = (const float*)d_in[0];
  const float* W_enc  = (const float*)d_in[2];
  const float* b_enc  = (const float*)d_in[3];
  const float* w_curv = (const float*)d_in[4];
  const float* b_curv = (const float*)d_in[5];
  const float* mem    = (const float*)d_in[6];
  const float* assoc  = (const float*)d_in[7];
  const float* W_dec  = (const float*)d_in[8];
  const float* b_dec  = (const float*)d_in[9];
  const float* temp   = (const float*)d_in[10];
  float* out = (float*)d_out;

  char* ws = (char*)d_ws;
  size_t off = 0;
  auto alloc = [&](size_t bytes) {
    void* p = ws + off;
    off += (bytes + 255) & ~(size_t)255;
    return p;
  };
  f16* Wt_hi   = (f16*)alloc((size_t)HD * DD * 2);   // W_enc^T hi [H,D]
  f16* Wt_lo   = (f16*)alloc((size_t)HD * DD * 2);   // W_enc^T lo [H,D]
  f16* ms_hi   = (f16*)alloc((size_t)MD * HD * 2);   // memory_slots hi [M,H]
  f16* ms_lo   = (f16*)alloc((size_t)MD * HD * 2);   // memory_slots lo [M,H]
  f16* assocT  = (f16*)alloc((size_t)MD * MD * 2);   // assoc^T [M,M]
  f16* WdT     = (f16*)alloc((size_t)DD * HD * 2);   // W_dec^T [D,H]
  float* query = (float*)alloc((size_t)BD * HD * 4);
  float* scale = (float*)alloc((size_t)BD * 4);
  float* sim   = (float*)alloc((size_t)BD * MD * 4); // reused as act1/act2
  int* idx     = (int*)alloc((size_t)BD * KD * 4);
  float* vals  = (float*)alloc((size_t)BD * KD * 4);
  f16* p_h     = (f16*)alloc((size_t)BD * MD * 2);
  f16* read_h  = (f16*)alloc((size_t)BD * HD * 2);
  float* out_b = (float*)alloc((size_t)BD * DD * 4);
  (void)ws_size; (void)in_sizes; (void)n_in; (void)out_size;

  dim3 b256(256);
  // operand prep
  k_transpose_split<<<dim3(HD / 32, DD / 32), b256, 0, stream>>>(W_enc, Wt_hi, Wt_lo, DD, HD);
  k_split<<<dim3((MD * HD / 8 + 255) / 256), b256, 0, stream>>>(mem, ms_hi, ms_lo, MD * HD / 8);
  k_transpose_f16<<<dim3(MD / 32, MD / 32), b256, 0, stream>>>(assoc, assocT, MD, MD);
  k_transpose_f16<<<dim3(DD / 32, HD / 32), b256, 0, stream>>>(W_dec, WdT, HD, DD);
  // enc GEMM (split-3, fp32-equivalent) + tanh + mean_s -> query [B,H]
  k_gemm_nt<1, 1><<<dim3(HD / 128, BD * SD / 128), b256, 0, stream>>>(
      x, Wt_hi, Wt_lo, query, b_enc, BD * SD, HD, DD);
  // gate scale per row
  k_gate<<<dim3(BD), b256, 0, stream>>>(query, w_curv, b_curv, temp, scale);
  // sim = query @ memory_slots^T (split-3, fp32-equivalent)  [B,M]
  k_gemm_nt<1, 0><<<dim3(MD / 128, BD / 128), b256, 0, stream>>>(
      query, ms_hi, ms_lo, sim, nullptr, BD, MD, HD);
  // top-32 (selection invariant to positive per-row scale; vals scaled after)
  k_topk<<<dim3(BD), b256, 0, stream>>>(sim, scale, idx, vals);
  // two rounds: softmax -> @ assoc  (fp16: act values ~1e-2 vs vals ~10)
  k_softmax<<<dim3(BD), b256, 0, stream>>>(sim, p_h, MD);
  k_gemm_nt<0, 0><<<dim3(MD / 128, BD / 128), b256, 0, stream>>>(
      p_h, assocT, nullptr, sim, nullptr, BD, MD, MD);
  k_softmax<<<dim3(BD), b256, 0, stream>>>(sim, p_h, MD);
  k_gemm_nt<0, 0><<<dim3(MD / 128, BD / 128), b256, 0, stream>>>(
      p_h, assocT, nullptr, sim, nullptr, BD, MD, MD);
  // combine softmax + weighted gather -> read [B,H] fp16
  k_combine<<<dim3(BD), b256, 0, stream>>>(vals, idx, sim, mem, read_h);
  // decode GEMM + tanh -> out_b [B,D]
  k_gemm_nt<0, 2><<<dim3(DD / 128, BD / 128), b256, 0, stream>>>(
      read_h, WdT, nullptr, out_b, b_dec, BD, DD, HD);
  // broadcast over S
  k_broadcast<<<dim3(BD * SD * DD / 1024), b256, 0, stream>>>(
      (const float4*)out_b, (float4*)out);
}

// Round 3
// 1407.288 us; speedup vs baseline: 1.0378x; 1.0378x over previous
//
#include <hip/hip_runtime.h>

typedef _Float16 f16;
typedef f16 f16x8 __attribute__((ext_vector_type(8)));
typedef float f32x4 __attribute__((ext_vector_type(4)));

#define BD 2048
#define SD 32
#define DD 1024
#define HD 1024
#define MD 4096
#define KD 32

// ---------- pack B (row-major [N,K] f32 source) into MFMA-frag-linear f16 hi(+lo) ----------
// frag order: [ntile][kc32][quad][l16][8 halfs] ; element = src[ntile*16+l16][kc32*32+quad*8+e]
__global__ void k_pack_rows(const float* __restrict__ in, f16* __restrict__ hi,
                            f16* __restrict__ lo, int N, int K) {
  int t = blockIdx.x * 256 + threadIdx.x;
  int total = (N >> 4) * (K >> 5) * 64;
  if (t >= total) return;
  int l16 = t & 15, quad = (t >> 4) & 3;
  int x = t >> 6;
  int kch = K >> 5;
  int kc = x % kch, nt = x / kch;
  const float* src = in + (size_t)(nt * 16 + l16) * K + kc * 32 + quad * 8;
  float4 u0 = *(const float4*)src;
  float4 u1 = *(const float4*)(src + 4);
  float v[8] = {u0.x, u0.y, u0.z, u0.w, u1.x, u1.y, u1.z, u1.w};
  f16x8 h, l;
#pragma unroll
  for (int e = 0; e < 8; ++e) {
    h[e] = (f16)v[e];
    l[e] = (f16)(v[e] - (float)h[e]);
  }
  ((f16x8*)hi)[t] = h;
  if (lo) ((f16x8*)lo)[t] = l;
}

// ---------- pack B = S^T where S is [K,N] f32 row-major ----------
__global__ void k_pack_T(const float* __restrict__ in, f16* __restrict__ hi,
                         f16* __restrict__ lo, int N, int K) {
  int t = blockIdx.x * 256 + threadIdx.x;
  int total = (N >> 4) * (K >> 5) * 64;
  if (t >= total) return;
  int l16 = t & 15, quad = (t >> 4) & 3;
  int x = t >> 6;
  int kch = K >> 5;
  int kc = x % kch, nt = x / kch;
  int col = nt * 16 + l16;          // B row index n
  int krow = kc * 32 + quad * 8;    // B col index k
  f16x8 h, l;
#pragma unroll
  for (int e = 0; e < 8; ++e) {
    float v = in[(size_t)(krow + e) * N + col];
    f16 hh = (f16)v;
    h[e] = hh;
    l[e] = (f16)(v - (float)hh);
  }
  ((f16x8*)hi)[t] = h;
  if (lo) ((f16x8*)lo)[t] = l;
}

// ---------------- NT GEMM: C[M,N] = A[M,K] * B[N,K]^T ----------------
// 256 thr = 4 waves; block tile 128x128; K-chunk 32; wave tile 64x64 (4x4 MFMA 16x16x32).
// A staged in LDS (unpadded 64B rows, XOR-16B-segment swizzle: seg ^= (row>>1)&3 -> 2-way=free).
// B fragments loaded DIRECTLY from frag-packed global (no LDS round-trip).
// SPLIT=1: A fp32 split hi/lo in staging; B pre-split (Bhi,Blo); 3-pass hh+hl+lh per kc
//          (fp32-equivalent; MFMA order identical to round-2 kernel -> bit-identical sim/topk).
// EPI 0: C[row,col]=v   EPI 1: tanh+bias, mean over 32-row groups   EPI 2: tanh+bias
// EPI 3: tanh+bias, broadcast-write to C[row*SD + s][col] for s in [0,SD)
template <int SPLIT, int EPI>
__global__ __launch_bounds__(256) void k_gemm(const void* __restrict__ Ap,
                                              const f16* __restrict__ Bhi,
                                              const f16* __restrict__ Blo,
                                              float* __restrict__ C,
                                              const float* __restrict__ bias,
                                              int M, int N, int K) {
  __shared__ f16 As[128 * 32];
  __shared__ f16 Asl[SPLIT ? 128 * 32 : 8];
  const int n0 = blockIdx.x * 128, m0 = blockIdx.y * 128;
  const int t = threadIdx.x;
  const int lane = t & 63, w = t >> 6;
  const int wm = w >> 1, wn = w & 1;
  const int quad = lane >> 4, l16 = lane & 15;
  const int srow = t >> 2, sseg = t & 3;     // staging: rows srow(+64), 8-half segment
  const int swf = (srow >> 1) & 3;           // staging-side xor swizzle
  const int rwf = (l16 >> 1) & 3;            // read-side xor swizzle
  const int kch = K >> 5;

  f32x4 acc[4][4] = {};

  for (int kc32 = 0; kc32 < kch; ++kc32) {
    const int kc = kc32 << 5;
    // ---- B fragments straight from packed global (L2/L3-resident) ----
    f16x8 bh[4], bl[4];
#pragma unroll
    for (int j = 0; j < 4; ++j) {
      size_t fi = (((size_t)((n0 >> 4) + wn * 4 + j) * kch + kc32) << 6) + (quad << 4) + l16;
      bh[j] = ((const f16x8*)Bhi)[fi];
      if (SPLIT) bl[j] = ((const f16x8*)Blo)[fi];
    }
    // ---- A tile staging into LDS (swizzled, conflict-free) ----
#pragma unroll
    for (int rep = 0; rep < 2; ++rep) {
      int row = srow + rep * 64;
      int slot = row * 32 + ((sseg ^ swf) << 3);
      if (SPLIT) {
        const float* g = (const float*)Ap + (size_t)(m0 + row) * K + kc + sseg * 8;
        float4 u0 = *(const float4*)g;
        float4 u1 = *(const float4*)(g + 4);
        float v[8] = {u0.x, u0.y, u0.z, u0.w, u1.x, u1.y, u1.z, u1.w};
        f16x8 h, l;
#pragma unroll
        for (int e = 0; e < 8; ++e) {
          h[e] = (f16)v[e];
          l[e] = (f16)(v[e] - (float)h[e]);
        }
        *(f16x8*)(As + slot) = h;
        *(f16x8*)(Asl + slot) = l;
      } else {
        const f16* g = (const f16*)Ap + (size_t)(m0 + row) * K + kc + sseg * 8;
        *(f16x8*)(As + slot) = *(const f16x8*)g;
      }
    }
    __syncthreads();
    // ---- A fragments from LDS ----
    f16x8 ah[4], al[4];
#pragma unroll
    for (int i = 0; i < 4; ++i) {
      int off = (wm * 64 + i * 16 + l16) * 32 + ((quad ^ rwf) << 3);
      ah[i] = *(const f16x8*)(As + off);
      if (SPLIT) al[i] = *(const f16x8*)(Asl + off);
    }
    // ---- MFMA (order identical to round 2: per (i,j): hh, hl, lh) ----
    if (SPLIT) {
#pragma unroll
      for (int i = 0; i < 4; ++i)
#pragma unroll
        for (int j = 0; j < 4; ++j) {
          acc[i][j] = __builtin_amdgcn_mfma_f32_16x16x32_f16(ah[i], bh[j], acc[i][j], 0, 0, 0);
          acc[i][j] = __builtin_amdgcn_mfma_f32_16x16x32_f16(ah[i], bl[j], acc[i][j], 0, 0, 0);
          acc[i][j] = __builtin_amdgcn_mfma_f32_16x16x32_f16(al[i], bh[j], acc[i][j], 0, 0, 0);
        }
    } else {
#pragma unroll
      for (int i = 0; i < 4; ++i)
#pragma unroll
        for (int j = 0; j < 4; ++j)
          acc[i][j] = __builtin_amdgcn_mfma_f32_16x16x32_f16(ah[i], bh[j], acc[i][j], 0, 0, 0);
    }
    __syncthreads();
  }

  if (EPI == 0) {
#pragma unroll
    for (int i = 0; i < 4; ++i) {
#pragma unroll
      for (int j = 0; j < 4; ++j) {
        int row = m0 + wm * 64 + i * 16 + quad * 4;
        int col = n0 + wn * 64 + j * 16 + l16;
        float* cp = C + (size_t)row * N + col;
#pragma unroll
        for (int r = 0; r < 4; ++r) cp[(size_t)r * N] = acc[i][j][r];
      }
    }
  } else if (EPI == 2) {
#pragma unroll
    for (int i = 0; i < 4; ++i) {
#pragma unroll
      for (int j = 0; j < 4; ++j) {
        int row = m0 + wm * 64 + i * 16 + quad * 4;
        int col = n0 + wn * 64 + j * 16 + l16;
        float bv = bias[col];
        float* cp = C + (size_t)row * N + col;
#pragma unroll
        for (int r = 0; r < 4; ++r) cp[(size_t)r * N] = tanhf(acc[i][j][r] + bv);
      }
    }
  } else if (EPI == 3) {  // tanh + bias + broadcast over SD
#pragma unroll
    for (int i = 0; i < 4; ++i) {
#pragma unroll
      for (int j = 0; j < 4; ++j) {
        int row = m0 + wm * 64 + i * 16 + quad * 4;
        int col = n0 + wn * 64 + j * 16 + l16;
        float bv = bias[col];
        float vv[4];
#pragma unroll
        for (int r = 0; r < 4; ++r) vv[r] = tanhf(acc[i][j][r] + bv);
        for (int s = 0; s < SD; ++s) {
          float* cp = C + ((size_t)row * SD + s) * N + col;
#pragma unroll
          for (int r = 0; r < 4; ++r) cp[(size_t)r * SD * N] = vv[r];
        }
      }
    }
  } else {  // EPI == 1: tanh + mean over 32-row groups
#pragma unroll
    for (int j = 0; j < 4; ++j) {
      int col = n0 + wn * 64 + j * 16 + l16;
      float bv = bias[col];
      float g0 = 0.f, g1 = 0.f;
#pragma unroll
      for (int i = 0; i < 4; ++i) {
        float s = 0.f;
#pragma unroll
        for (int r = 0; r < 4; ++r) s += tanhf(acc[i][j][r] + bv);
        if (i < 2) g0 += s; else g1 += s;
      }
      g0 += __shfl_xor(g0, 16); g0 += __shfl_xor(g0, 32);
      g1 += __shfl_xor(g1, 16); g1 += __shfl_xor(g1, 32);
      if (quad == 0) {
        int grp = (m0 + wm * 64) >> 5;
        C[(size_t)grp * N + col] = g0 * (1.0f / 32.0f);
        C[(size_t)(grp + 1) * N + col] = g1 * (1.0f / 32.0f);
      }
    }
  }
}

// ---------------- gate: scale[b] = (0.5 + sigmoid(q.w_curv + b_curv)) / max(temp,1e-6) --------
__global__ void k_gate(const float* __restrict__ query, const float* __restrict__ w_curv,
                       const float* __restrict__ b_curv, const float* __restrict__ temp,
                       float* __restrict__ scale) {
  int b = blockIdx.x, t = threadIdx.x;
  float s = 0.f;
  for (int h = t; h < HD; h += 256) s += query[(size_t)b * HD + h] * w_curv[h];
#pragma unroll
  for (int off = 32; off; off >>= 1) s += __shfl_xor(s, off);
  __shared__ float red[4];
  if ((t & 63) == 0) red[t >> 6] = s;
  __syncthreads();
  if (t == 0) {
    float tot = red[0] + red[1] + red[2] + red[3] + b_curv[0];
    float g = 1.f / (1.f + expf(-tot));
    scale[b] = (0.5f + g) / fmaxf(temp[0], 1e-6f);
  }
}

// ---------------- top-32 per row (iterative argmax in LDS) ----------------
__global__ void k_topk(const float* __restrict__ sim, const float* __restrict__ scale,
                       int* __restrict__ idx, float* __restrict__ vals) {
  int b = blockIdx.x, t = threadIdx.x;
  __shared__ float sv[MD];
  __shared__ float rv[4];
  __shared__ int ri[4];
  for (int i = t; i < MD; i += 256) sv[i] = sim[(size_t)b * MD + i];
  __syncthreads();
  float sc = scale[b];
  for (int k = 0; k < KD; ++k) {
    float bv = -1e30f;
    int bi = 0x7fffffff;
    for (int i = t; i < MD; i += 256) {
      float v = sv[i];
      if (v > bv) { bv = v; bi = i; }
    }
#pragma unroll
    for (int off = 1; off < 64; off <<= 1) {
      float ov = __shfl_xor(bv, off);
      int oi = __shfl_xor(bi, off);
      if (ov > bv || (ov == bv && oi < bi)) { bv = ov; bi = oi; }
    }
    if ((t & 63) == 0) { rv[t >> 6] = bv; ri[t >> 6] = bi; }
    __syncthreads();
    if (t == 0) {
      float fv = rv[0];
      int fi = ri[0];
#pragma unroll
      for (int u = 1; u < 4; ++u)
        if (rv[u] > fv || (rv[u] == fv && ri[u] < fi)) { fv = rv[u]; fi = ri[u]; }
      idx[b * KD + k] = fi;
      vals[b * KD + k] = fv * sc;
      sv[fi] = -1e30f;
    }
    __syncthreads();
  }
}

// ---------------- row softmax f32 -> f16 ----------------
__global__ void k_softmax(const float* __restrict__ in, f16* __restrict__ out, int C) {
  int b = blockIdx.x, t = threadIdx.x;
  const float* row = in + (size_t)b * C;
  __shared__ float red[4];
  float m = -1e30f;
  for (int i = t; i < C; i += 256) m = fmaxf(m, row[i]);
#pragma unroll
  for (int off = 32; off; off >>= 1) m = fmaxf(m, __shfl_xor(m, off));
  if ((t & 63) == 0) red[t >> 6] = m;
  __syncthreads();
  m = fmaxf(fmaxf(red[0], red[1]), fmaxf(red[2], red[3]));
  __syncthreads();
  float s = 0.f;
  for (int i = t; i < C; i += 256) s += expf(row[i] - m);
#pragma unroll
  for (int off = 32; off; off >>= 1) s += __shfl_xor(s, off);
  if ((t & 63) == 0) red[t >> 6] = s;
  __syncthreads();
  s = red[0] + red[1] + red[2] + red[3];
  float inv = 1.f / s;
  for (int i = t; i < C; i += 256) out[(size_t)b * C + i] = (f16)(expf(row[i] - m) * inv);
}

// ---------------- combine: softmax(vals + act[idx]) weighted gather of memory_slots --------
__global__ void k_combine(const float* __restrict__ vals, const int* __restrict__ idx,
                          const float* __restrict__ act, const float* __restrict__ mem,
                          f16* __restrict__ read_h) {
  int b = blockIdx.x, t = threadIdx.x;
  __shared__ float comb[KD];
  __shared__ int sidx[KD];
  if (t < KD) {
    int id = idx[b * KD + t];
    sidx[t] = id;
    float e = vals[b * KD + t] + act[(size_t)b * MD + id];
    float m = e;
#pragma unroll
    for (int off = 16; off; off >>= 1) m = fmaxf(m, __shfl_xor(m, off));
    float p = expf(e - m);
    float s = p;
#pragma unroll
    for (int off = 16; off; off >>= 1) s += __shfl_xor(s, off);
    comb[t] = p / s;
  }
  __syncthreads();
  for (int h = t; h < HD; h += 256) {
    float a = 0.f;
#pragma unroll
    for (int k = 0; k < KD; ++k) a += comb[k] * mem[(size_t)sidx[k] * HD + h];
    read_h[(size_t)b * HD + h] = (f16)a;
  }
}

extern "C" void kernel_launch(void* const* d_in, const int* in_sizes, int n_in,
                              void* d_out, int out_size, void* d_ws, size_t ws_size,
                              hipStream_t stream) {
  const float* x      = (const float*)d_in[0];
  const float* W_enc  = (const float*)d_in[2];
  const float* b_enc  = (const float*)d_in[3];
  const float* w_curv = (const float*)d_in[4];
  const float* b_curv = (const float*)d_in[5];
  const float* mem    = (const float*)d_in[6];
  const float* assoc  = (const float*)d_in[7];
  const float* W_dec  = (const float*)d_in[8];
  const float* b_dec  = (const float*)d_in[9];
  const float* temp   = (const float*)d_in[10];
  float* out = (float*)d_out;

  char* ws = (char*)d_ws;
  size_t off = 0;
  auto alloc = [&](size_t bytes) {
    void* p = ws + off;
    off += (bytes + 255) & ~(size_t)255;
    return p;
  };
  f16* Wt_hi   = (f16*)alloc((size_t)HD * DD * 2);   // W_enc^T frag-packed hi
  f16* Wt_lo   = (f16*)alloc((size_t)HD * DD * 2);
  f16* ms_hi   = (f16*)alloc((size_t)MD * HD * 2);   // memory_slots frag-packed hi
  f16* ms_lo   = (f16*)alloc((size_t)MD * HD * 2);
  f16* as_pk   = (f16*)alloc((size_t)MD * MD * 2);   // assoc^T frag-packed
  f16* wd_pk   = (f16*)alloc((size_t)HD * DD * 2);   // W_dec^T frag-packed
  float* query = (float*)alloc((size_t)BD * HD * 4);
  float* scale = (float*)alloc((size_t)BD * 4);
  float* sim   = (float*)alloc((size_t)BD * MD * 4); // reused as act1/act2
  int* idx     = (int*)alloc((size_t)BD * KD * 4);
  float* vals  = (float*)alloc((size_t)BD * KD * 4);
  f16* p_h     = (f16*)alloc((size_t)BD * MD * 2);
  f16* read_h  = (f16*)alloc((size_t)BD * HD * 2);
  (void)ws_size; (void)in_sizes; (void)n_in; (void)out_size;

  dim3 b256(256);
  // ---- operand frag-packing ----
  k_pack_T<<<dim3((HD / 16) * (DD / 32) * 64 / 256), b256, 0, stream>>>(W_enc, Wt_hi, Wt_lo, HD, DD);
  k_pack_rows<<<dim3((MD / 16) * (HD / 32) * 64 / 256), b256, 0, stream>>>(mem, ms_hi, ms_lo, MD, HD);
  k_pack_T<<<dim3((MD / 16) * (MD / 32) * 64 / 256), b256, 0, stream>>>(assoc, as_pk, nullptr, MD, MD);
  k_pack_T<<<dim3((DD / 16) * (HD / 32) * 64 / 256), b256, 0, stream>>>(W_dec, wd_pk, nullptr, DD, HD);
  // ---- enc GEMM (split-3) + tanh + mean_s -> query [B,H] ----
  k_gemm<1, 1><<<dim3(HD / 128, BD * SD / 128), b256, 0, stream>>>(
      x, Wt_hi, Wt_lo, query, b_enc, BD * SD, HD, DD);
  // ---- gate scale per row ----
  k_gate<<<dim3(BD), b256, 0, stream>>>(query, w_curv, b_curv, temp, scale);
  // ---- sim = query @ memory_slots^T (split-3) ----
  k_gemm<1, 0><<<dim3(MD / 128, BD / 128), b256, 0, stream>>>(
      query, ms_hi, ms_lo, sim, nullptr, BD, MD, HD);
  // ---- top-32 ----
  k_topk<<<dim3(BD), b256, 0, stream>>>(sim, scale, idx, vals);
  // ---- two rounds: softmax -> @ assoc ----
  k_softmax<<<dim3(BD), b256, 0, stream>>>(sim, p_h, MD);
  k_gemm<0, 0><<<dim3(MD / 128, BD / 128), b256, 0, stream>>>(
      p_h, as_pk, nullptr, sim, nullptr, BD, MD, MD);
  k_softmax<<<dim3(BD), b256, 0, stream>>>(sim, p_h, MD);
  k_gemm<0, 0><<<dim3(MD / 128, BD / 128), b256, 0, stream>>>(
      p_h, as_pk, nullptr, sim, nullptr, BD, MD, MD);
  // ---- combine softmax + weighted gather -> read [B,H] f16 ----
  k_combine<<<dim3(BD), b256, 0, stream>>>(vals, idx, sim, mem, read_h);
  // ---- decode GEMM + tanh + fused broadcast over S -> out [B,S,D] ----
  k_gemm<0, 3><<<dim3(DD / 128, BD / 128), b256, 0, stream>>>(
      read_h, wd_pk, nullptr, out, b_dec, BD, DD, HD);
}